// Round 1
// baseline (445.489 us; speedup 1.0000x reference)
//
#include <hip/hip_runtime.h>
#include <hip/hip_bf16.h>

// ArcFace head: out[b,c] = S * margin(clip(dot(f_b, w_c)/(|f_b||w_c|)))
// Single fused kernel: bf16 MFMA GEMM with fp32 accum; per-row norms
// accumulated during fp32->bf16 staging; margin + scale in epilogue.

typedef __attribute__((ext_vector_type(8))) short short8;
typedef __attribute__((ext_vector_type(8))) unsigned short u16x8;
typedef __attribute__((ext_vector_type(4))) float f32x4;

#define TH_CONST  (-0.8775825618903728f)   // cos(pi - 0.5)
#define MM_CONST  (0.23971276930210156f)   // sin(pi - 0.5) * 0.5
#define M_MARGIN  0.5f
#define S_SCALE   64.0f

#define BM 128
#define BN 128
#define BK 32
#define KD 512   // feature dim (fixed by problem)

__device__ __forceinline__ unsigned short f2bf(float x) {
    // round-to-nearest-even fp32 -> bf16 (inputs are finite gaussians; no NaN path)
    unsigned int u = __float_as_uint(x);
    u += 0x7fffu + ((u >> 16) & 1u);
    return (unsigned short)(u >> 16);
}

__global__ __launch_bounds__(256, 2)
void arcface_kernel(const float* __restrict__ F,     // [512][512]
                    const int*   __restrict__ labels,// [512]
                    const float* __restrict__ W,     // [C][512]
                    float*       __restrict__ Out,   // [512][C]
                    const int C)
{
    __shared__ unsigned short As[BM][BK];   // 8 KB bf16 feature tile
    __shared__ unsigned short Bs[BN][BK];   // 8 KB bf16 weight tile
    __shared__ float normF[BM];
    __shared__ float normW[BN];
    __shared__ int   Ls[BM];

    const int t = threadIdx.x;
    const int m_base = blockIdx.x * BM;     // grid.x = 4 (m fastest -> weight-tile L2 reuse)
    const int n_base = blockIdx.y * BN;     // grid.y = 782

    if (t < BM) Ls[t] = labels[m_base + t];

    // staging assignment: thread t covers row r (0..127), k-half h (16 floats)
    const int r = t >> 1;
    const int h = t & 1;

    const int lane = t & 63;
    const int wave = t >> 6;
    const int wm = (wave >> 1) * 64;        // wave quadrant rows
    const int wn = (wave & 1) * 64;         // wave quadrant cols
    const int quad = lane >> 4;
    const int lcol = lane & 15;

    f32x4 acc[4][4];
    #pragma unroll
    for (int i = 0; i < 4; ++i)
        #pragma unroll
        for (int j = 0; j < 4; ++j)
            acc[i][j] = (f32x4){0.f, 0.f, 0.f, 0.f};

    const int cls = n_base + r;
    const bool cvalid = (cls < C);

    const float* Arow = F + (size_t)(m_base + r) * KD + h * 16;
    const float* Wrow = W + (size_t)(cvalid ? cls : 0) * KD + h * 16;

    float sF = 0.f, sW = 0.f;   // partial sum-of-squares (this thread's 16-elem slices)

    for (int kt = 0; kt < KD / BK; ++kt) {
        // ---- global loads (fp32), issued before the barrier for overlap ----
        const float4* ap = (const float4*)(Arow + kt * BK);
        const float4* wp = (const float4*)(Wrow + kt * BK);
        float4 a0 = ap[0], a1 = ap[1], a2 = ap[2], a3 = ap[3];
        float4 w0, w1, w2, w3;
        if (cvalid) { w0 = wp[0]; w1 = wp[1]; w2 = wp[2]; w3 = wp[3]; }
        else {
            w0 = make_float4(0.f,0.f,0.f,0.f); w1 = w0; w2 = w0; w3 = w0;
        }

        // norms from the original fp32 values (matches reference numerics)
        sF += a0.x*a0.x + a0.y*a0.y + a0.z*a0.z + a0.w*a0.w
            + a1.x*a1.x + a1.y*a1.y + a1.z*a1.z + a1.w*a1.w
            + a2.x*a2.x + a2.y*a2.y + a2.z*a2.z + a2.w*a2.w
            + a3.x*a3.x + a3.y*a3.y + a3.z*a3.z + a3.w*a3.w;
        sW += w0.x*w0.x + w0.y*w0.y + w0.z*w0.z + w0.w*w0.w
            + w1.x*w1.x + w1.y*w1.y + w1.z*w1.z + w1.w*w1.w
            + w2.x*w2.x + w2.y*w2.y + w2.z*w2.z + w2.w*w2.w
            + w3.x*w3.x + w3.y*w3.y + w3.z*w3.z + w3.w*w3.w;

        // ---- convert to bf16, pack to 16B vectors ----
        u16x8 pa0, pa1, pb0, pb1;
        pa0[0]=f2bf(a0.x); pa0[1]=f2bf(a0.y); pa0[2]=f2bf(a0.z); pa0[3]=f2bf(a0.w);
        pa0[4]=f2bf(a1.x); pa0[5]=f2bf(a1.y); pa0[6]=f2bf(a1.z); pa0[7]=f2bf(a1.w);
        pa1[0]=f2bf(a2.x); pa1[1]=f2bf(a2.y); pa1[2]=f2bf(a2.z); pa1[3]=f2bf(a2.w);
        pa1[4]=f2bf(a3.x); pa1[5]=f2bf(a3.y); pa1[6]=f2bf(a3.z); pa1[7]=f2bf(a3.w);
        pb0[0]=f2bf(w0.x); pb0[1]=f2bf(w0.y); pb0[2]=f2bf(w0.z); pb0[3]=f2bf(w0.w);
        pb0[4]=f2bf(w1.x); pb0[5]=f2bf(w1.y); pb0[6]=f2bf(w1.z); pb0[7]=f2bf(w1.w);
        pb1[0]=f2bf(w2.x); pb1[1]=f2bf(w2.y); pb1[2]=f2bf(w2.z); pb1[3]=f2bf(w2.w);
        pb1[4]=f2bf(w3.x); pb1[5]=f2bf(w3.y); pb1[6]=f2bf(w3.z); pb1[7]=f2bf(w3.w);

        __syncthreads();   // previous iteration's fragment reads complete
        *((u16x8*)&As[r][h*16])     = pa0;
        *((u16x8*)&As[r][h*16 + 8]) = pa1;
        *((u16x8*)&Bs[r][h*16])     = pb0;
        *((u16x8*)&Bs[r][h*16 + 8]) = pb1;
        __syncthreads();   // tiles visible

        // ---- fragments + MFMA ----
        // A[m=lane&15][k=quad*8+j], B[n=lane&15][k=quad*8+j]
        short8 af[4], bfr[4];
        #pragma unroll
        for (int i = 0; i < 4; ++i) {
            af[i]  = *(const short8*)&As[wm + i*16 + lcol][quad*8];
            bfr[i] = *(const short8*)&Bs[wn + i*16 + lcol][quad*8];
        }
        #pragma unroll
        for (int i = 0; i < 4; ++i)
            #pragma unroll
            for (int j = 0; j < 4; ++j)
                acc[i][j] = __builtin_amdgcn_mfma_f32_16x16x32_bf16(
                                af[i], bfr[j], acc[i][j], 0, 0, 0);
    }

    // ---- finish norms: pair (h=0,h=1) are adjacent lanes ----
    sF += __shfl_xor(sF, 1);
    sW += __shfl_xor(sW, 1);
    if (h == 0) {
        normF[r] = 1.0f / sqrtf(sF + 1e-12f);
        normW[r] = 1.0f / sqrtf(sW + 1e-12f);
    }
    __syncthreads();

    // ---- epilogue: C/D layout col=lane&15, row=quad*4+reg ----
    #pragma unroll
    for (int mi = 0; mi < 4; ++mi) {
        const int rl_base = wm + mi*16 + quad*4;
        #pragma unroll
        for (int rg = 0; rg < 4; ++rg) {
            const int rl = rl_base + rg;
            const float invf = normF[rl];
            const int lbl = Ls[rl];
            float* orow = Out + (size_t)(m_base + rl) * C;
            #pragma unroll
            for (int ni = 0; ni < 4; ++ni) {
                const int cl = wn + ni*16 + lcol;
                const int gcol = n_base + cl;
                if (gcol < C) {
                    float v = acc[mi][ni][rg] * invf * normW[cl];
                    v = fminf(1.0f, fmaxf(-1.0f, v));
                    if (gcol == lbl) {
                        v = (v > TH_CONST) ? cosf(acosf(v) + M_MARGIN)
                                           : (v - MM_CONST);
                    }
                    orow[gcol] = S_SCALE * v;
                }
            }
        }
    }
}

extern "C" void kernel_launch(void* const* d_in, const int* in_sizes, int n_in,
                              void* d_out, int out_size, void* d_ws, size_t ws_size,
                              hipStream_t stream) {
    const float* F      = (const float*)d_in[0];
    const int*   labels = (const int*)d_in[1];
    const float* W      = (const float*)d_in[2];
    float*       Out    = (float*)d_out;

    const int B = in_sizes[1];          // 512
    const int C = in_sizes[2] / KD;     // 100000

    dim3 grid(B / BM, (C + BN - 1) / BN);   // (4, 782); m fastest for weight L2 reuse
    arcface_kernel<<<grid, dim3(256), 0, stream>>>(F, labels, W, Out, C);
}